// Round 1
// baseline (1557.415 us; speedup 1.0000x reference)
//
#include <hip/hip_runtime.h>
#include <stdint.h>

typedef __bf16 bf16;
typedef __bf16 bf16x8 __attribute__((ext_vector_type(8)));
typedef __bf16 bf16x4 __attribute__((ext_vector_type(4)));
typedef float  f32x4  __attribute__((ext_vector_type(4)));

#define B_   4
#define S_   1024
#define D_   1024
#define H_   16
#define DH_  64
#define DFF_ 4096
#define NL_  4
#define M_   (B_*S_)   // 4096 rows of activations

// ---------------------------------------------------------------------------
// async global->LDS copy, 16B per lane. LDS dest must be wave-uniform base;
// lane i lands at base + i*16 bytes (guide §5 caveat).
// ---------------------------------------------------------------------------
__device__ __forceinline__ void async_copy16(const void* g, void* l) {
  __builtin_amdgcn_global_load_lds(
      (const __attribute__((address_space(1))) char*)(uintptr_t)g,
      (__attribute__((address_space(3))) char*)(uintptr_t)l,
      16, 0, 0);
}

// ---------------------------------------------------------------------------
// GEMM (BT form): C[M,N] = A[M,K] @ W[N,K]^T + bias, optional relu,
// output fp32 or bf16. 128x128 tile, BK=32, 4 waves in 2x2 quadrants,
// mfma_f32_16x16x32_bf16, global_load_lds width=16 staging (m97 structure).
// All dims divisible by 128/32 in this problem.
// ---------------------------------------------------------------------------
template<int RELU, int OUT_BF16>
__global__ __launch_bounds__(256) void gemm_bt_kernel(
    const bf16* __restrict__ A,     // [M,K] row-major bf16
    const bf16* __restrict__ W,     // [N,K] row-major bf16
    const float* __restrict__ bias, // [N]
    float* __restrict__ Cf,         // used if !OUT_BF16
    bf16*  __restrict__ Cb,         // used if OUT_BF16
    int N, int K)
{
  __shared__ bf16 As[128*32];  // [row][k] row-major, 8KB
  __shared__ bf16 Bs[128*32];

  const int tid  = threadIdx.x;
  const int wave = tid >> 6;
  const int lane = tid & 63;
  const int wr = wave >> 1, wc = wave & 1;   // 2x2 wave grid -> 64x64 quadrant
  const int q4  = lane >> 4;                 // quad 0..3
  const int l15 = lane & 15;
  const int bm = blockIdx.y << 7, bn = blockIdx.x << 7;

  // staging: each wave covers 32 rows of A and 32 rows of W per K-step,
  // two 16-row issues of 64 lanes x 16B each.
  const bf16* ag  = A + (size_t)(bm + wave*32 + (lane >> 2))*K + (lane & 3)*8;
  const bf16* wgp = W + (size_t)(bn + wave*32 + (lane >> 2))*K + (lane & 3)*8;
  bf16* asw = As + wave*(32*32);
  bf16* bsw = Bs + wave*(32*32);

  // fragment read offsets (A-operand layout: A[m=l15][k=q4*8+j], 16B reads)
  const int a_off = (wr*64 + l15)*32 + q4*8;
  const int b_off = (wc*64 + l15)*32 + q4*8;

  f32x4 acc[4][4] = {};

  for (int k0 = 0; k0 < K; k0 += 32) {
    async_copy16(ag,                 asw);
    async_copy16(ag + (size_t)16*K,  asw + 16*32);
    async_copy16(wgp,                bsw);
    async_copy16(wgp + (size_t)16*K, bsw + 16*32);
    ag += 32; wgp += 32;
    __syncthreads();   // drains vmcnt -> staged data visible

    bf16x8 af[4], bfg[4];
#pragma unroll
    for (int r = 0; r < 4; ++r) af[r]  = *(const bf16x8*)(As + a_off + r*16*32);
#pragma unroll
    for (int c = 0; c < 4; ++c) bfg[c] = *(const bf16x8*)(Bs + b_off + c*16*32);
#pragma unroll
    for (int r = 0; r < 4; ++r)
#pragma unroll
      for (int c = 0; c < 4; ++c)
        acc[r][c] = __builtin_amdgcn_mfma_f32_16x16x32_bf16(af[r], bfg[c], acc[r][c], 0, 0, 0);
    __syncthreads();   // all reads done before next stage overwrites
  }

  // epilogue: C/D layout col=lane&15, row=quad*4+reg (guide §3, m89-verified)
#pragma unroll
  for (int r = 0; r < 4; ++r) {
    const int row0 = bm + wr*64 + r*16 + q4*4;
#pragma unroll
    for (int c = 0; c < 4; ++c) {
      const int col = bn + wc*64 + c*16 + l15;
      const float bv = bias[col];
#pragma unroll
      for (int i = 0; i < 4; ++i) {
        float v = acc[r][c][i] + bv;
        if (RELU) v = fmaxf(v, 0.f);
        if (OUT_BF16) Cb[(size_t)(row0 + i)*N + col] = (bf16)v;
        else          Cf[(size_t)(row0 + i)*N + col] = v;
      }
    }
  }
}

// ---------------------------------------------------------------------------
// Flash-style block-causal attention. One workgroup per (qblock, b*H+h).
// BLK==64 == tile, so no intra-tile masking: key tiles 0..qb are fully valid.
// LDS rows padded to 72 elements (144B = 9*16B): keeps 16B alignment for
// b128 reads and <=2-way bank conflicts (free, m136).
// ---------------------------------------------------------------------------
#define LP 72
__global__ __launch_bounds__(256) void attn_kernel(
    const bf16* __restrict__ qkv,  // [M, 3*D] rows b*S+s; Q|K|V col blocks
    bf16* __restrict__ out)        // [M, D]
{
  const int qb  = blockIdx.x;          // 0..15
  const int bh  = blockIdx.y;          // 0..63
  const int b   = bh >> 4, h = bh & 15;
  const int tid = threadIdx.x;
  const int wave = tid >> 6, lane = tid & 63;
  const int q4 = lane >> 4, l15 = lane & 15;

  __shared__ bf16 Qs[64*LP];
  __shared__ bf16 Ks[64*LP];
  __shared__ bf16 Vt[64*LP];       // transposed: Vt[d][n]
  __shared__ bf16 Ps[4][16*LP];    // per-wave P strip (C-layout -> A-layout)

  const size_t RS = 3*(size_t)D_;  // qkv row stride
  const bf16* qbase = qkv + ((size_t)(b*S_ + qb*64))*RS + h*64;

  // load Q tile: 512 chunks of 8 bf16, 2 per thread
  {
    int cidx = tid;
#pragma unroll
    for (int it = 0; it < 2; ++it, cidx += 256) {
      int r = cidx >> 3, co = (cidx & 7)*8;
      *(bf16x8*)&Qs[r*LP + co] = *(const bf16x8*)&qbase[(size_t)r*RS + co];
    }
  }

  f32x4 o_acc[4] = {};
  float m_i[4], l_i[4];
#pragma unroll
  for (int i = 0; i < 4; ++i) { m_i[i] = -1e30f; l_i[i] = 0.f; }
  const float scale = 0.125f;   // 1/sqrt(64)

  for (int kt = 0; kt <= qb; ++kt) {
    __syncthreads();  // prev compute done (also covers Q load on first iter)
    const bf16* kbase = qkv + ((size_t)(b*S_ + kt*64))*RS + D_   + h*64;
    const bf16* vbase = qkv + ((size_t)(b*S_ + kt*64))*RS + 2*D_ + h*64;
    {
      int cidx = tid;
#pragma unroll
      for (int it = 0; it < 2; ++it, cidx += 256) {
        int r = cidx >> 3, co = (cidx & 7)*8;
        *(bf16x8*)&Ks[r*LP + co] = *(const bf16x8*)&kbase[(size_t)r*RS + co];
        bf16x8 v = *(const bf16x8*)&vbase[(size_t)r*RS + co];
#pragma unroll
        for (int j = 0; j < 8; ++j) Vt[(co + j)*LP + r] = v[j];
      }
    }
    __syncthreads();

    // S = Q @ K^T  (wave covers 16 query rows: wave*16 + l15)
    f32x4 s[4] = {};
#pragma unroll
    for (int d0 = 0; d0 < 64; d0 += 32) {
      bf16x8 aq = *(const bf16x8*)&Qs[(wave*16 + l15)*LP + d0 + q4*8];
#pragma unroll
      for (int c = 0; c < 4; ++c) {
        bf16x8 bk = *(const bf16x8*)&Ks[(c*16 + l15)*LP + d0 + q4*8];
        s[c] = __builtin_amdgcn_mfma_f32_16x16x32_bf16(aq, bk, s[c], 0, 0, 0);
      }
    }
#pragma unroll
    for (int c = 0; c < 4; ++c)
#pragma unroll
      for (int i = 0; i < 4; ++i) s[c][i] *= scale;

    // online softmax per register-row i (row = wave*16 + q4*4 + i)
#pragma unroll
    for (int i = 0; i < 4; ++i) {
      float mx = -1e30f;
#pragma unroll
      for (int c = 0; c < 4; ++c) mx = fmaxf(mx, s[c][i]);
#pragma unroll
      for (int off = 1; off < 16; off <<= 1) mx = fmaxf(mx, __shfl_xor(mx, off, 64));
      float m_new = fmaxf(m_i[i], mx);
      float alpha = __expf(m_i[i] - m_new);
      float rowsum = 0.f;
#pragma unroll
      for (int c = 0; c < 4; ++c) {
        float p = __expf(s[c][i] - m_new);
        Ps[wave][(q4*4 + i)*LP + c*16 + l15] = (bf16)p;
        rowsum += p;
      }
#pragma unroll
      for (int off = 1; off < 16; off <<= 1) rowsum += __shfl_xor(rowsum, off, 64);
      l_i[i] = l_i[i]*alpha + rowsum;
      m_i[i] = m_new;
#pragma unroll
      for (int c = 0; c < 4; ++c) o_acc[c][i] *= alpha;
    }

    // O += P @ V   (Ps is wave-private: no barrier; compiler orders LDS deps)
#pragma unroll
    for (int n0 = 0; n0 < 64; n0 += 32) {
      bf16x8 ap = *(const bf16x8*)&Ps[wave][l15*LP + n0 + q4*8];
#pragma unroll
      for (int c = 0; c < 4; ++c) {
        bf16x8 bv = *(const bf16x8*)&Vt[(c*16 + l15)*LP + n0 + q4*8];
        o_acc[c] = __builtin_amdgcn_mfma_f32_16x16x32_bf16(ap, bv, o_acc[c], 0, 0, 0);
      }
    }
  }

  // epilogue: normalize and store (out col = h*64 + d)
  bf16* obase = out + ((size_t)(b*S_ + qb*64 + wave*16))*D_ + h*64;
#pragma unroll
  for (int i = 0; i < 4; ++i) {
    float inv = 1.f / l_i[i];
#pragma unroll
    for (int c = 0; c < 4; ++c)
      obase[(size_t)(q4*4 + i)*D_ + c*16 + l15] = (bf16)(o_acc[c][i]*inv);
  }
}

// ---------------------------------------------------------------------------
// residual add + LayerNorm (fp32 stats), writes fp32 x, bf16 x, optional copy
// ---------------------------------------------------------------------------
__global__ __launch_bounds__(256) void add_ln_kernel(
    const float* __restrict__ xin, const float* __restrict__ yin,
    const float* __restrict__ w, const float* __restrict__ bta,
    float* __restrict__ xout, bf16* __restrict__ xbf,
    float* __restrict__ extra)
{
  const int row = blockIdx.x;
  const int tid = threadIdx.x;
  const size_t base = (size_t)row * D_;
  float v[4], s = 0.f, ss = 0.f;
#pragma unroll
  for (int j = 0; j < 4; ++j) {
    int idx = tid + j*256;
    v[j] = xin[base + idx] + yin[base + idx];
    s += v[j]; ss += v[j]*v[j];
  }
#pragma unroll
  for (int off = 1; off < 64; off <<= 1) {
    s  += __shfl_xor(s,  off, 64);
    ss += __shfl_xor(ss, off, 64);
  }
  __shared__ float red[8];
  const int wave = tid >> 6, lane = tid & 63;
  if (lane == 0) { red[wave] = s; red[4 + wave] = ss; }
  __syncthreads();
  s  = red[0] + red[1] + red[2] + red[3];
  ss = red[4] + red[5] + red[6] + red[7];
  const float mean = s * (1.f/D_);
  const float var  = ss * (1.f/D_) - mean*mean;
  const float rstd = rsqrtf(var + 1e-5f);
#pragma unroll
  for (int j = 0; j < 4; ++j) {
    int idx = tid + j*256;
    float o = (v[j] - mean)*rstd*w[idx] + bta[idx];
    xout[base + idx] = o;
    xbf[base + idx]  = (bf16)o;
    if (extra) extra[base + idx] = o;
  }
}

// ---------------------------------------------------------------------------
// fp32 -> bf16 conversion (vectorized, grid-stride)
// ---------------------------------------------------------------------------
__global__ __launch_bounds__(256) void conv_kernel(
    const float4* __restrict__ src, bf16x4* __restrict__ dst, int n4)
{
  int i = blockIdx.x*blockDim.x + threadIdx.x;
  const int stride = gridDim.x*blockDim.x;
  for (; i < n4; i += stride) {
    float4 f = src[i];
    bf16x4 o;
    o[0] = (bf16)f.x; o[1] = (bf16)f.y; o[2] = (bf16)f.z; o[3] = (bf16)f.w;
    dst[i] = o;
  }
}

__global__ __launch_bounds__(256) void init_x_kernel(
    const float4* __restrict__ src, float4* __restrict__ xf,
    bf16x4* __restrict__ xb, int n4)
{
  int i = blockIdx.x*blockDim.x + threadIdx.x;
  const int stride = gridDim.x*blockDim.x;
  for (; i < n4; i += stride) {
    float4 f = src[i];
    xf[i] = f;
    bf16x4 o;
    o[0] = (bf16)f.x; o[1] = (bf16)f.y; o[2] = (bf16)f.z; o[3] = (bf16)f.w;
    xb[i] = o;
  }
}

// ---------------------------------------------------------------------------
extern "C" void kernel_launch(void* const* d_in, const int* in_sizes, int n_in,
                              void* d_out, int out_size, void* d_ws, size_t ws_size,
                              hipStream_t stream) {
  const float* x    = (const float*)d_in[0];
  const float* inw  = (const float*)d_in[1];
  const float* inb  = (const float*)d_in[2];
  const float* outw = (const float*)d_in[3];
  const float* outb = (const float*)d_in[4];
  const float* ln1w = (const float*)d_in[5];
  const float* ln1b = (const float*)d_in[6];
  const float* l1w  = (const float*)d_in[7];
  const float* l1b  = (const float*)d_in[8];
  const float* l2w  = (const float*)d_in[9];
  const float* l2b  = (const float*)d_in[10];
  const float* ln2w = (const float*)d_in[11];
  const float* ln2b = (const float*)d_in[12];

  char* ws = (char*)d_ws;
  size_t off = 0;
  auto take = [&](size_t bytes) {
    char* p = ws + off;
    off = (off + bytes + 255) & ~(size_t)255;
    return p;
  };
  bf16*  w_in_bf  = (bf16*) take((size_t)NL_*3*D_*D_*2);
  bf16*  w_out_bf = (bf16*) take((size_t)NL_*D_*D_*2);
  bf16*  w_l1_bf  = (bf16*) take((size_t)NL_*DFF_*D_*2);
  bf16*  w_l2_bf  = (bf16*) take((size_t)NL_*D_*DFF_*2);
  float* x_f      = (float*)take((size_t)M_*D_*4);
  bf16*  x_b      = (bf16*) take((size_t)M_*D_*2);
  bf16*  qkv_b    = (bf16*) take((size_t)M_*3*D_*2);
  bf16*  at_b     = (bf16*) take((size_t)M_*D_*2);
  bf16*  h_b      = (bf16*) take((size_t)M_*DFF_*2);
  float* tmp_f    = (float*)take((size_t)M_*D_*4);
  (void)ws_size; (void)in_sizes; (void)n_in;

  auto conv = [&](const float* s, bf16* d, size_t n) {
    int n4 = (int)(n >> 2);
    int grid = (n4 + 255) / 256; if (grid > 4096) grid = 4096;
    conv_kernel<<<grid, 256, 0, stream>>>((const float4*)s, (bf16x4*)d, n4);
  };
  conv(inw,  w_in_bf,  (size_t)NL_*3*D_*D_);
  conv(outw, w_out_bf, (size_t)NL_*D_*D_);
  conv(l1w,  w_l1_bf,  (size_t)NL_*DFF_*D_);
  conv(l2w,  w_l2_bf,  (size_t)NL_*D_*DFF_);
  init_x_kernel<<<4096, 256, 0, stream>>>((const float4*)x, (float4*)x_f,
                                          (bf16x4*)x_b, (int)((size_t)M_*D_ >> 2));

  for (int l = 0; l < NL_; ++l) {
    // qkv = x @ in_proj_w^T + b   [4096,3072] bf16
    gemm_bt_kernel<0,1><<<dim3(3*D_/128, M_/128), 256, 0, stream>>>(
        x_b, w_in_bf + (size_t)l*3*D_*D_, inb + (size_t)l*3*D_,
        nullptr, qkv_b, 3*D_, D_);
    // attention -> at_b [4096,1024] bf16
    attn_kernel<<<dim3(S_/64, B_*H_), 256, 0, stream>>>(qkv_b, at_b);
    // o = attn @ out_w^T + b -> tmp_f fp32
    gemm_bt_kernel<0,0><<<dim3(D_/128, M_/128), 256, 0, stream>>>(
        at_b, w_out_bf + (size_t)l*D_*D_, outb + (size_t)l*D_,
        tmp_f, nullptr, D_, D_);
    // x = LN(x + o)
    add_ln_kernel<<<M_, 256, 0, stream>>>(
        x_f, tmp_f, ln1w + (size_t)l*D_, ln1b + (size_t)l*D_,
        x_f, x_b, nullptr);
    // h = relu(x @ lin1^T + b) [4096,4096] bf16
    gemm_bt_kernel<1,1><<<dim3(DFF_/128, M_/128), 256, 0, stream>>>(
        x_b, w_l1_bf + (size_t)l*DFF_*D_, l1b + (size_t)l*DFF_,
        nullptr, h_b, DFF_, D_);
    // f = h @ lin2^T + b -> tmp_f fp32   (K = 4096)
    gemm_bt_kernel<0,0><<<dim3(D_/128, M_/128), 256, 0, stream>>>(
        h_b, w_l2_bf + (size_t)l*D_*DFF_, l2b + (size_t)l*D_,
        tmp_f, nullptr, D_, DFF_);
    // x = LN(x + f); last layer also writes d_out
    add_ln_kernel<<<M_, 256, 0, stream>>>(
        x_f, tmp_f, ln2w + (size_t)l*D_, ln2b + (size_t)l*D_,
        x_f, x_b, (l == NL_-1) ? (float*)d_out : nullptr);
  }
}